// Round 8
// baseline (17.788 us; speedup 1.0000x reference)
//
#include <hip/hip_runtime.h>
#include <math.h>

#define DIM 128
#define KAPPA 20.0f
#define NB    512         // K1 blocks
#define ROWS  32          // rows per K1 block
#define SLOTS 16          // candidate slots per block
#define SCAP  64          // max survivors in finisher

// ---------------------------------------------------------------------------
// K1: 512 blocks x 512 threads (8 waves), 32 rows per block.
// Wave w handles 4 rows (base = b*32 + w*4) via TWO float4 loads:
//   load A: lanes 0-31 -> row base   (float4 idx lane&31), lanes 32-63 -> base+1
//   load B: same for rows base+2 / base+3.
// Half-wave butterfly (masks 16..1 stay within each 32-lane half) gives every
// lane its half's row sum; full-wave max + cross-half shfl for the rest.
// Streaming logsumexp per block: maxb[b], Sb[b] = sum expf(k*nn - k*maxb_b)
// (double). Conservative candidate superset via LOCAL max threshold
// (g(nmax)=nmax-5.2/nmax increasing => superset of global filter) into
// per-block slots. cnt[b] written unconditionally (poison-proof, no memset).
// ---------------------------------------------------------------------------
__global__ void HubPass1_kernel(const float* __restrict__ E,
                                float* __restrict__ maxb,
                                double* __restrict__ Sb,
                                int* __restrict__ cnt,
                                int2* __restrict__ slots,  // (idx, nn-bits)
                                int n) {
    __shared__ float wred[8];
    __shared__ double dred[8];
    __shared__ float s_maxb;
    __shared__ int   s_cnt;
    int b = blockIdx.x, tid = threadIdx.x;
    int lane = tid & 63, wave = tid >> 6;      // 8 waves
    int half = lane >> 5;                      // 0 or 1

    if (tid == 0) s_cnt = 0;

    int base = b * ROWS + wave * 4;            // first of 4 rows
    // load A: rows base+half ; load B: rows base+2+half
    const float4* pA = (const float4*)(E + (size_t)(base + half) * DIM) + (lane & 31);
    const float4* pB = (const float4*)(E + (size_t)(base + 2 + half) * DIM) + (lane & 31);
    float4 va = pA[0];
    float4 vb = pB[0];
    float sA = va.x * va.x + va.y * va.y + va.z * va.z + va.w * va.w;
    float sB = vb.x * vb.x + vb.y * vb.y + vb.z * vb.z + vb.w * vb.w;
    #pragma unroll
    for (int m = 16; m >= 1; m >>= 1) {        // within 32-lane halves
        sA += __shfl_xor(sA, m, 64);
        sB += __shfl_xor(sB, m, 64);
    }
    // lanes in half 0 hold sums of rows base / base+2; half 1: base+1 / base+3

    float wmax = fmaxf(sA, sB);
    #pragma unroll
    for (int m = 32; m >= 1; m >>= 1) wmax = fmaxf(wmax, __shfl_xor(wmax, m, 64));
    if (lane == 0) wred[wave] = wmax;
    __syncthreads();
    if (tid == 0) {
        float r = wred[0];
        #pragma unroll
        for (int i = 1; i < 8; ++i) r = fmaxf(r, wred[i]);
        s_maxb = r;
        maxb[b] = r;
    }
    __syncthreads();
    float mb = s_maxb;
    float Mb = KAPPA * mb;
    float thr = mb - 104.0f / KAPPA;           // local (conservative) threshold

    // exp terms: every lane computes its half's two rows (redundant across the
    // half, free under SIMT); combine halves with one cross-half shuffle.
    float  eA = expf(KAPPA * sA - Mb);
    float  eB = expf(KAPPA * sB - Mb);
    double d  = (double)eA + (double)eB;       // rows {base+half, base+2+half}
    d += __shfl_xor(d, 32, 64);                // + other half's two rows
    if (lane == 0) dred[wave] = d;

    // candidate filter: lane 0 covers rows base/base+2, lane 32 covers +1/+3
    if ((lane & 31) == 0) {
        if (sqrtf(sA * mb) >= thr) {
            int k = atomicAdd(&s_cnt, 1);
            if (k < SLOTS) {
                int2 e; e.x = base + half; e.y = __float_as_int(sA);
                slots[b * SLOTS + k] = e;
            }
        }
        if (sqrtf(sB * mb) >= thr) {
            int k = atomicAdd(&s_cnt, 1);
            if (k < SLOTS) {
                int2 e; e.x = base + 2 + half; e.y = __float_as_int(sB);
                slots[b * SLOTS + k] = e;
            }
        }
    }
    __syncthreads();
    if (tid == 0) {
        double S = 0.0;
        #pragma unroll
        for (int i = 0; i < 8; ++i) S += dred[i];
        Sb[b] = S;
        cnt[b] = min(s_cnt, SLOTS);
    }
}

// ---------------------------------------------------------------------------
// K2: ONE block x 1024 threads.
// M = k*max(maxb[512]); S_diag = sum Sb[b]*exp(k*(maxb[b]-max)) (double,
// fixed order); re-filter slots with the GLOBAL threshold (same predicate as
// the proven filter -> same survivor set); sort; exact pair dots (weight 2);
// out = M + log(S).
// ---------------------------------------------------------------------------
__global__ void HubFinal_kernel(const float* __restrict__ E,
                                const float* __restrict__ maxb,
                                const double* __restrict__ Sb,
                                const int* __restrict__ cnt,
                                const int2* __restrict__ slots,
                                float* __restrict__ out, int n) {
    __shared__ float mred[8];
    __shared__ float s_max2;
    __shared__ double dred8[8];
    __shared__ double s_diag;
    __shared__ double dred[16];
    __shared__ int   cntS[NB];
    __shared__ int   s_c;
    __shared__ int   surv[SCAP];

    int tid = threadIdx.x;                 // 0..1023
    int lane = tid & 63, wave = tid >> 6;  // 16 waves

    if (tid == 0) s_c = 0;
    if (tid < NB) cntS[tid] = cnt[tid];

    // --- global max over maxb[512] (waves 0..7) ---
    float m = (tid < NB) ? maxb[tid] : 0.f;
    #pragma unroll
    for (int s = 32; s >= 1; s >>= 1) m = fmaxf(m, __shfl_xor(m, s, 64));
    if (tid < NB && lane == 0) mred[wave] = m;
    __syncthreads();
    if (tid == 0) {
        float r = mred[0];
        #pragma unroll
        for (int i = 1; i < 8; ++i) r = fmaxf(r, mred[i]);
        s_max2 = r;
    }
    __syncthreads();
    float maxn2 = s_max2;
    float M = KAPPA * maxn2;
    float thr = maxn2 - 104.0f / KAPPA;    // global (exact) threshold

    // --- S_diag = sum Sb[b] * exp(KAPPA*(maxb[b]-maxn2)), fixed order ---
    double d = 0.0;
    if (tid < NB)
        d = Sb[tid] * exp((double)KAPPA * ((double)maxb[tid] - (double)maxn2));
    #pragma unroll
    for (int s = 32; s >= 1; s >>= 1) d += __shfl_xor(d, s, 64);
    if (tid < NB && lane == 0) dred8[wave] = d;
    __syncthreads();
    if (tid == 0) {
        double S = 0.0;
        #pragma unroll
        for (int i = 0; i < 8; ++i) S += dred8[i];
        s_diag = S;
    }

    // --- re-filter candidate slots with global threshold ---
    #pragma unroll
    for (int q = 0; q < 8; ++q) {
        int s = tid * 8 + q;               // 512*16 = 8192 slots
        int b = s >> 4, j = s & 15;
        if (j < cntS[b]) {
            int2 e = slots[s];
            float nn = __int_as_float(e.y);
            if (sqrtf(nn * maxn2) >= thr) {
                int k = atomicAdd(&s_c, 1);
                if (k < SCAP) surv[k] = e.x;
            }
        }
    }
    __syncthreads();
    int c = min(s_c, SCAP);
    if (tid == 0) {                        // sort tiny list for determinism
        for (int a = 1; a < c; ++a) {
            int v = surv[a], bb = a - 1;
            while (bb >= 0 && surv[bb] > v) { surv[bb + 1] = surv[bb]; --bb; }
            surv[bb + 1] = v;
        }
    }
    __syncthreads();

    // --- exact off-diagonal pair terms (weight 2 by symmetry) ---
    double local = 0.0;
    int idx = 0;
    for (int a = 0; a < c; ++a) {
        for (int bb = a + 1; bb < c; ++bb, ++idx) {
            if ((idx & 1023) != tid) continue;
            const float4* pa = (const float4*)(E + (size_t)surv[a] * DIM);
            const float4* pb = (const float4*)(E + (size_t)surv[bb] * DIM);
            float dot = 0.f;
            #pragma unroll
            for (int k = 0; k < DIM / 4; ++k) {
                float4 x = pa[k], y = pb[k];
                dot += x.x * y.x + x.y * y.y + x.z * y.z + x.w * y.w;
            }
            local += 2.0 * (double)expf(KAPPA * dot - M);
        }
    }
    #pragma unroll
    for (int s = 32; s >= 1; s >>= 1) local += __shfl_xor(local, s, 64);
    if (lane == 0) dred[wave] = local;
    __syncthreads();
    if (tid == 0) {
        double S = s_diag;
        #pragma unroll
        for (int i = 0; i < 16; ++i) S += dred[i];
        out[0] = M + logf((float)S);
    }
}

extern "C" void kernel_launch(void* const* d_in, const int* in_sizes, int n_in,
                              void* d_out, int out_size, void* d_ws, size_t ws_size,
                              hipStream_t stream) {
    const float* E = (const float*)d_in[0];
    int n = in_sizes[0] / DIM;               // 16384
    float* out = (float*)d_out;

    char* base = (char*)d_ws;
    float*  maxb  = (float*)base;                // 512*4 = 2K  @ 0
    double* Sb    = (double*)(base + 2048);      // 512*8 = 4K  @ 2K
    int*    cnt   = (int*)(base + 6144);         // 512*4 = 2K  @ 6K
    int2*   slots = (int2*)(base + 8192);        // 512*16*8 = 64K @ 8K

    hipLaunchKernelGGL(HubPass1_kernel, dim3(NB), dim3(512), 0, stream,
                       E, maxb, Sb, cnt, slots, n);
    hipLaunchKernelGGL(HubFinal_kernel, dim3(1), dim3(1024), 0, stream,
                       E, maxb, Sb, cnt, slots, out, n);
}

// Round 9
// 17.038 us; speedup vs baseline: 1.0440x; 1.0440x over previous
//
#include <hip/hip_runtime.h>
#include <math.h>

#define DIM 128
#define KAPPA 20.0f
#define SLOTS 16          // candidate slots per block
#define SCAP  64          // max survivors in finisher

// ---------------------------------------------------------------------------
// K1: 256 blocks x 1024 threads (16 waves), 64 rows per block.
// Wave w, rows b*64 + w*4 + r (r=0..3): float2/lane coalesced load,
// butterfly reduce -> row squared-norm in registers (never written).
// Then per block: maxb[b]; S_b = sum expf(k*nn - k*maxb_b) (double, fixed
// order); conservative candidate superset via LOCAL max threshold
// (g(nmax)=nmax-5.2/nmax is increasing => local filter is a superset of the
// global one) stored into per-block slots. No global atomics, no memset:
// cnt[b] is written unconditionally each launch (poison-proof).
// ---------------------------------------------------------------------------
__global__ void HubPass1_kernel(const float* __restrict__ E,
                                float* __restrict__ maxb,
                                double* __restrict__ Sb,
                                int* __restrict__ cnt,
                                int2* __restrict__ slots,  // (idx, nn-bits)
                                int n) {
    __shared__ float wred[16];
    __shared__ double dred[16];
    __shared__ float s_maxb;
    __shared__ int   s_cnt;
    int b = blockIdx.x, tid = threadIdx.x;
    int lane = tid & 63, wave = tid >> 6;

    if (tid == 0) s_cnt = 0;

    float s_r[4];
    #pragma unroll
    for (int r = 0; r < 4; ++r) {
        int row = b * 64 + wave * 4 + r;
        float s = 0.f;
        if (row < n) {
            const float2* p = (const float2*)(E + (size_t)row * DIM);
            float2 v = p[lane];
            s = v.x * v.x + v.y * v.y;
        }
        #pragma unroll
        for (int m = 32; m >= 1; m >>= 1) s += __shfl_xor(s, m, 64);
        s_r[r] = s;                       // all lanes hold the row sum
    }
    float wmax = fmaxf(fmaxf(s_r[0], s_r[1]), fmaxf(s_r[2], s_r[3]));
    if (lane == 0) wred[wave] = wmax;
    __syncthreads();
    if (tid == 0) {
        float r = wred[0];
        #pragma unroll
        for (int i = 1; i < 16; ++i) r = fmaxf(r, wred[i]);
        s_maxb = r;
        maxb[b] = r;
    }
    __syncthreads();
    float mb = s_maxb;
    float Mb = KAPPA * mb;
    float thr = mb - 104.0f / KAPPA;      // local (conservative) threshold

    if (lane == 0) {
        double d = 0.0;
        #pragma unroll
        for (int r = 0; r < 4; ++r) {
            float nn = s_r[r];
            d += (double)expf(KAPPA * nn - Mb);
            if (sqrtf(nn * mb) >= thr) {
                int k = atomicAdd(&s_cnt, 1);
                if (k < SLOTS) {
                    int2 e; e.x = b * 64 + wave * 4 + r;
                    e.y = __float_as_int(nn);
                    slots[b * SLOTS + k] = e;
                }
            }
        }
        dred[wave] = d;
    }
    __syncthreads();
    if (tid == 0) {
        double S = 0.0;
        #pragma unroll
        for (int i = 0; i < 16; ++i) S += dred[i];
        Sb[b] = S;
        cnt[b] = min(s_cnt, SLOTS);
    }
}

// ---------------------------------------------------------------------------
// K2: ONE block x 1024 threads.
// M = k*max(maxb); S_diag = sum Sb[b]*exp(k*(maxb[b]-max)) (double, fixed
// order); re-filter candidate slots with the GLOBAL threshold (predicate
// identical to the proven R3 filter -> same survivor set); sort survivors;
// exact pair dots (weight 2 by symmetry); out = M + log(S).
// ---------------------------------------------------------------------------
__global__ void HubFinal_kernel(const float* __restrict__ E,
                                const float* __restrict__ maxb,
                                const double* __restrict__ Sb,
                                const int* __restrict__ cnt,
                                const int2* __restrict__ slots,
                                float* __restrict__ out, int n) {
    __shared__ float mred[4];
    __shared__ float s_max2;
    __shared__ double dred4[4];
    __shared__ double s_diag;
    __shared__ double dred[16];
    __shared__ int   cntS[256];
    __shared__ int   s_c;
    __shared__ int   surv[SCAP];

    int tid = threadIdx.x;                // 0..1023
    int lane = tid & 63, wave = tid >> 6; // 16 waves

    if (tid == 0) s_c = 0;
    if (tid < 256) cntS[tid] = cnt[tid];

    // --- global max over maxb[256] (waves 0..3) ---
    float m = (tid < 256) ? maxb[tid] : 0.f;
    #pragma unroll
    for (int s = 32; s >= 1; s >>= 1) m = fmaxf(m, __shfl_xor(m, s, 64));
    if (tid < 256 && lane == 0) mred[wave] = m;
    __syncthreads();
    if (tid == 0)
        s_max2 = fmaxf(fmaxf(mred[0], mred[1]), fmaxf(mred[2], mred[3]));
    __syncthreads();
    float maxn2 = s_max2;
    float M = KAPPA * maxn2;
    float thr = maxn2 - 104.0f / KAPPA;   // global (exact) threshold

    // --- S_diag = sum Sb[b] * exp(KAPPA*(maxb[b]-maxn2)), fixed order ---
    double d = 0.0;
    if (tid < 256)
        d = Sb[tid] * exp((double)KAPPA * ((double)maxb[tid] - (double)maxn2));
    #pragma unroll
    for (int s = 32; s >= 1; s >>= 1) d += __shfl_xor(d, s, 64);
    if (tid < 256 && lane == 0) dred4[wave] = d;
    __syncthreads();
    if (tid == 0)
        s_diag = dred4[0] + dred4[1] + dred4[2] + dred4[3];

    // --- re-filter candidate slots with global threshold ---
    #pragma unroll
    for (int q = 0; q < 4; ++q) {
        int s = tid * 4 + q;              // 4096 slots
        int b = s >> 4, j = s & 15;
        if (j < cntS[b]) {
            int2 e = slots[s];
            float nn = __int_as_float(e.y);
            if (sqrtf(nn * maxn2) >= thr) {
                int k = atomicAdd(&s_c, 1);
                if (k < SCAP) surv[k] = e.x;
            }
        }
    }
    __syncthreads();
    int c = min(s_c, SCAP);
    if (tid == 0) {                       // sort tiny list for determinism
        for (int a = 1; a < c; ++a) {
            int v = surv[a], bb = a - 1;
            while (bb >= 0 && surv[bb] > v) { surv[bb + 1] = surv[bb]; --bb; }
            surv[bb + 1] = v;
        }
    }
    __syncthreads();

    // --- exact off-diagonal pair terms (weight 2 by symmetry) ---
    double local = 0.0;
    int idx = 0;
    for (int a = 0; a < c; ++a) {
        for (int bb = a + 1; bb < c; ++bb, ++idx) {
            if ((idx & 1023) != tid) continue;
            const float4* pa = (const float4*)(E + (size_t)surv[a] * DIM);
            const float4* pb = (const float4*)(E + (size_t)surv[bb] * DIM);
            float dot = 0.f;
            #pragma unroll
            for (int k = 0; k < DIM / 4; ++k) {
                float4 x = pa[k], y = pb[k];
                dot += x.x * y.x + x.y * y.y + x.z * y.z + x.w * y.w;
            }
            local += 2.0 * (double)expf(KAPPA * dot - M);
        }
    }
    #pragma unroll
    for (int s = 32; s >= 1; s >>= 1) local += __shfl_xor(local, s, 64);
    if (lane == 0) dred[wave] = local;
    __syncthreads();
    if (tid == 0) {
        double S = s_diag;
        #pragma unroll
        for (int i = 0; i < 16; ++i) S += dred[i];
        out[0] = M + logf((float)S);
    }
}

extern "C" void kernel_launch(void* const* d_in, const int* in_sizes, int n_in,
                              void* d_out, int out_size, void* d_ws, size_t ws_size,
                              hipStream_t stream) {
    const float* E = (const float*)d_in[0];
    int n = in_sizes[0] / DIM;               // 16384
    float* out = (float*)d_out;

    char* base = (char*)d_ws;
    float*  maxb  = (float*)base;                // 256*4  @ 0
    double* Sb    = (double*)(base + 1024);      // 256*8  @ 1K
    int*    cnt   = (int*)(base + 3072);         // 256*4  @ 3K
    int2*   slots = (int2*)(base + 4096);        // 256*16*8 = 32K @ 4K

    hipLaunchKernelGGL(HubPass1_kernel, dim3(256), dim3(1024), 0, stream,
                       E, maxb, Sb, cnt, slots, n);
    hipLaunchKernelGGL(HubFinal_kernel, dim3(1), dim3(1024), 0, stream,
                       E, maxb, Sb, cnt, slots, out, n);
}